// Round 1
// baseline (3186.118 us; speedup 1.0000x reference)
//
#include <hip/hip_runtime.h>
#include <hip/hip_fp16.h>

// Problem constants
#define BB 64
#define TT 2048
#define II 128
#define HH 128
#define NG 512  // 4*H

typedef _Float16 h2_t __attribute__((ext_vector_type(2)));

#if defined(__has_builtin)
#if __has_builtin(__builtin_amdgcn_fdot2)
#define HAVE_FDOT2 1
#endif
#endif

__device__ __forceinline__ float fdot2f(h2_t a, h2_t b, float c) {
#ifdef HAVE_FDOT2
  return __builtin_amdgcn_fdot2(a, b, c, false);
#else
  return c + (float)a[0] * (float)b[0] + (float)a[1] * (float)b[1];
#endif
}

__device__ __forceinline__ float fast_sigmoid(float x) {
  float t = __builtin_amdgcn_exp2f(-1.4426950408889634f * x);
  return __builtin_amdgcn_rcpf(1.0f + t);
}

__device__ __forceinline__ float fast_tanh(float x) {
  float xx = fminf(fmaxf(x, -32.0f), 32.0f);
  float e = __builtin_amdgcn_exp2f(2.8853900817779268f * xx);
  return (e - 1.0f) * __builtin_amdgcn_rcpf(e + 1.0f);
}

union F4H {
  float4 f4;
  h2_t h[4];
};

// ---------------------------------------------------------------------------
// Transpose Wx0 [512][128] -> WT [128][512] (fp32), tiny
// ---------------------------------------------------------------------------
__global__ void wx0_transpose(const float* __restrict__ W, float* __restrict__ WT) {
  int idx = blockIdx.x * 256 + threadIdx.x;
  if (idx < NG * II) {
    int n = idx >> 7;
    int k = idx & 127;
    WT[k * NG + n] = W[idx];
  }
}

// ---------------------------------------------------------------------------
// Xg0 = x @ Wx0^T + b0, stored as f16.  C[M=131072, N=512], K=128.
// BM=64, BN=64, full-K tiles in LDS.
// ---------------------------------------------------------------------------
__global__ __launch_bounds__(256) void xg0_gemm(const float* __restrict__ X,
                                                const float* __restrict__ WT,  // [128][512]
                                                const float* __restrict__ bias,
                                                __half* __restrict__ Xg) {
  __shared__ float As[64][132];  // [m][k], padded; 132*4=528, 16B-aligned rows
  __shared__ float Bs[128][64];  // [k][n]
  const int m0 = blockIdx.x * 64;
  const int n0 = blockIdx.y * 64;
  const int tid = threadIdx.x;

  // Load A tile: 64 rows x 128 k, coalesced float4
  {
    const float4* xv = (const float4*)(X + (size_t)m0 * II);
#pragma unroll
    for (int r = 0; r < 8; ++r) {
      int f = tid + 256 * r;
      int m = f >> 5;
      int c4 = f & 31;
      float4 v = xv[m * 32 + c4];
      *(float4*)&As[m][c4 * 4] = v;
    }
  }
  // Load B tile from WT: 128 k x 64 n, coalesced float4
  {
#pragma unroll
    for (int r = 0; r < 8; ++r) {
      int f = tid + 256 * r;
      int k = f >> 4;
      int q = f & 15;
      float4 v = *(const float4*)(WT + (size_t)k * NG + n0 + q * 4);
      *(float4*)&Bs[k][q * 4] = v;
    }
  }
  __syncthreads();

  const int tx = tid & 15;
  const int ty = tid >> 4;
  float acc[4][4];
#pragma unroll
  for (int i = 0; i < 4; ++i)
#pragma unroll
    for (int j = 0; j < 4; ++j) acc[i][j] = 0.0f;

#pragma unroll 4
  for (int k = 0; k < 128; ++k) {
    float a0 = As[ty * 4 + 0][k];
    float a1 = As[ty * 4 + 1][k];
    float a2 = As[ty * 4 + 2][k];
    float a3 = As[ty * 4 + 3][k];
    float4 bv = *(const float4*)&Bs[k][tx * 4];
    acc[0][0] = fmaf(a0, bv.x, acc[0][0]);
    acc[0][1] = fmaf(a0, bv.y, acc[0][1]);
    acc[0][2] = fmaf(a0, bv.z, acc[0][2]);
    acc[0][3] = fmaf(a0, bv.w, acc[0][3]);
    acc[1][0] = fmaf(a1, bv.x, acc[1][0]);
    acc[1][1] = fmaf(a1, bv.y, acc[1][1]);
    acc[1][2] = fmaf(a1, bv.z, acc[1][2]);
    acc[1][3] = fmaf(a1, bv.w, acc[1][3]);
    acc[2][0] = fmaf(a2, bv.x, acc[2][0]);
    acc[2][1] = fmaf(a2, bv.y, acc[2][1]);
    acc[2][2] = fmaf(a2, bv.z, acc[2][2]);
    acc[2][3] = fmaf(a2, bv.w, acc[2][3]);
    acc[3][0] = fmaf(a3, bv.x, acc[3][0]);
    acc[3][1] = fmaf(a3, bv.y, acc[3][1]);
    acc[3][2] = fmaf(a3, bv.z, acc[3][2]);
    acc[3][3] = fmaf(a3, bv.w, acc[3][3]);
  }

  // Epilogue: add bias, convert to f16, store
  float4 bvec = *(const float4*)(bias + n0 + tx * 4);
#pragma unroll
  for (int i = 0; i < 4; ++i) {
    int m = m0 + ty * 4 + i;
    __half2* dst = (__half2*)(Xg + (size_t)m * NG + n0 + tx * 4);
    dst[0] = __halves2half2(__float2half(acc[i][0] + bvec.x),
                            __float2half(acc[i][1] + bvec.y));
    dst[1] = __halves2half2(__float2half(acc[i][2] + bvec.z),
                            __float2half(acc[i][3] + bvec.w));
  }
}

// ---------------------------------------------------------------------------
// Recurrence: one workgroup per batch element. 512 threads, thread n owns
// gate row n for both layers. Weights (f16) live in registers:
//   wh0[64] (layer0 Wh row), wx1[64] + wh1[64] (layer1 Wx|Wh rows) = 192 VGPR.
// h0/h1 kept in LDS as f16 pairs; c kept in fp32 registers of threads n<128.
// ---------------------------------------------------------------------------
__global__ __launch_bounds__(512, 2) void lstm_rec(
    const __half* __restrict__ Xg0,   // [B*T][512], includes b0
    const float* __restrict__ Wh0,    // [512][128]
    const float* __restrict__ Wx1,    // [512][128]
    const float* __restrict__ Wh1,    // [512][128]
    const float* __restrict__ b1,     // [512]
    float* __restrict__ out)          // output | hT | cT
{
  const int b = blockIdx.x;
  const int n = threadIdx.x;

  // Load per-thread weight rows, convert to f16 pairs (registers)
  h2_t wh0[64], wx1[64], wh1[64];
  {
    const float2* p0 = (const float2*)(Wh0 + (size_t)n * HH);
    const float2* p1 = (const float2*)(Wx1 + (size_t)n * HH);
    const float2* p2 = (const float2*)(Wh1 + (size_t)n * HH);
#pragma unroll
    for (int j = 0; j < 64; ++j) {
      float2 v0 = p0[j];
      float2 v1 = p1[j];
      float2 v2 = p2[j];
      wh0[j][0] = (_Float16)v0.x; wh0[j][1] = (_Float16)v0.y;
      wx1[j][0] = (_Float16)v1.x; wx1[j][1] = (_Float16)v1.y;
      wh1[j][0] = (_Float16)v2.x; wh1[j][1] = (_Float16)v2.y;
    }
  }
  const float bias1 = b1[n];

  __shared__ __align__(16) h2_t h0p[64];
  __shared__ __align__(16) h2_t h1p[64];
  __shared__ float g0[512];
  __shared__ float g1[512];

  if (n < 64) {
    h2_t z;
    z[0] = (_Float16)0.0f;
    z[1] = (_Float16)0.0f;
    h0p[n] = z;
    h1p[n] = z;
  }
  float c0 = 0.0f, c1 = 0.0f;
  __syncthreads();

  const __half* xgp = Xg0 + (size_t)b * TT * NG + n;
  float* outp = out + (size_t)b * TT * HH;
  float* hT = out + (size_t)BB * TT * HH;       // [2][64][128]
  float* cT = hT + 2 * BB * HH;                 // [2][64][128]

  __half xg_next = xgp[0];
  float h0new = 0.0f;

  for (int t = 0; t < TT; ++t) {
    // ---- Layer 0: gates0[n] = Xg0 + Wh0[n,:] . h0 ----
    float acc = __half2float(xg_next);
#pragma unroll
    for (int q = 0; q < 16; ++q) {
      F4H u;
      u.f4 = *(const float4*)&h0p[q * 4];
      acc = fdot2f(wh0[4 * q + 0], u.h[0], acc);
      acc = fdot2f(wh0[4 * q + 1], u.h[1], acc);
      acc = fdot2f(wh0[4 * q + 2], u.h[2], acc);
      acc = fdot2f(wh0[4 * q + 3], u.h[3], acc);
    }
    g0[n] = acc;
    __syncthreads();

    // ---- Layer 0 elementwise (threads 0..127) ----
    if (n < 128) {
      float gi = fast_sigmoid(g0[n]);
      float gf = fast_sigmoid(g0[n + 128]);
      float gg = fast_tanh(g0[n + 256]);
      float go = fast_sigmoid(g0[n + 384]);
      c0 = gf * c0 + gi * gg;
      h0new = go * fast_tanh(c0);
      ((_Float16*)h0p)[n] = (_Float16)h0new;
    }
    __syncthreads();

    // prefetch next step's Xg0 element (hidden under L1 dots)
    if (t + 1 < TT) xg_next = xgp[(size_t)(t + 1) * NG];

    // ---- Layer 1: gates1[n] = b1 + Wx1[n,:].h0_new + Wh1[n,:].h1 ----
    float a1 = bias1;
#pragma unroll
    for (int q = 0; q < 16; ++q) {
      F4H u;
      u.f4 = *(const float4*)&h0p[q * 4];
      a1 = fdot2f(wx1[4 * q + 0], u.h[0], a1);
      a1 = fdot2f(wx1[4 * q + 1], u.h[1], a1);
      a1 = fdot2f(wx1[4 * q + 2], u.h[2], a1);
      a1 = fdot2f(wx1[4 * q + 3], u.h[3], a1);
    }
#pragma unroll
    for (int q = 0; q < 16; ++q) {
      F4H u;
      u.f4 = *(const float4*)&h1p[q * 4];
      a1 = fdot2f(wh1[4 * q + 0], u.h[0], a1);
      a1 = fdot2f(wh1[4 * q + 1], u.h[1], a1);
      a1 = fdot2f(wh1[4 * q + 2], u.h[2], a1);
      a1 = fdot2f(wh1[4 * q + 3], u.h[3], a1);
    }
    g1[n] = a1;
    __syncthreads();

    // ---- Layer 1 elementwise + output write (threads 0..127) ----
    if (n < 128) {
      float gi = fast_sigmoid(g1[n]);
      float gf = fast_sigmoid(g1[n + 128]);
      float gg = fast_tanh(g1[n + 256]);
      float go = fast_sigmoid(g1[n + 384]);
      c1 = gf * c1 + gi * gg;
      float h1new = go * fast_tanh(c1);
      ((_Float16*)h1p)[n] = (_Float16)h1new;
      outp[(size_t)t * HH + n] = h1new;
      if (t == TT - 1) {
        hT[b * HH + n] = h0new;
        hT[BB * HH + b * HH + n] = h1new;
        cT[b * HH + n] = c0;
        cT[BB * HH + b * HH + n] = c1;
      }
    }
    __syncthreads();
  }
}

// ---------------------------------------------------------------------------
extern "C" void kernel_launch(void* const* d_in, const int* in_sizes, int n_in,
                              void* d_out, int out_size, void* d_ws, size_t ws_size,
                              hipStream_t stream) {
  const float* x   = (const float*)d_in[0];
  const float* Wx0 = (const float*)d_in[1];
  const float* Wh0 = (const float*)d_in[2];
  const float* b0  = (const float*)d_in[3];
  const float* Wx1 = (const float*)d_in[4];
  const float* Wh1 = (const float*)d_in[5];
  const float* b1  = (const float*)d_in[6];
  float* out = (float*)d_out;

  // Workspace layout: Xg0 f16 [B*T][512] = 128 MB, then WT fp32 [128][512]
  __half* Xg = (__half*)d_ws;
  float* WT = (float*)((char*)d_ws + (size_t)BB * TT * NG * sizeof(__half));

  wx0_transpose<<<(NG * II + 255) / 256, 256, 0, stream>>>(Wx0, WT);
  xg0_gemm<<<dim3((BB * TT) / 64, NG / 64), 256, 0, stream>>>(x, WT, b0, Xg);
  lstm_rec<<<BB, 512, 0, stream>>>(Xg, Wh0, Wx1, Wh1, b1, out);
}